// Round 16
// baseline (240.756 us; speedup 1.0000x reference)
//
#include <hip/hip_runtime.h>
#include <hip/hip_bf16.h>
#include <cstdint>
#include <cstddef>

// TwoLayerGAT on MI355X — round 16:
//  - gemm2: in-block split-K. 512 threads = 8 waves; wave-group kb=t>>8 computes
//    K-half kb with its own round-14-proven BK=32 double-buffer (32KB each).
//    16 block-wide barriers (was 32) AND 2x waves/CU. Final combine via the
//    dead staging LDS (group0 dumps f32 acc, group1 adds + runs epilogue).
//  - everything else identical to round 14 (211us baseline).

#define EDD 32

typedef __attribute__((ext_vector_type(4))) float f32x4;
typedef __attribute__((ext_vector_type(8))) short bf16x8;
typedef __attribute__((ext_vector_type(8))) unsigned short u16x8;

__device__ inline unsigned short f2bf_rn(float f) {
  uint32_t u = __float_as_uint(f);
  return (unsigned short)((u + 0x7FFFu + ((u >> 16) & 1u)) >> 16);
}

__device__ inline float bf2f(unsigned short b) {
  return __uint_as_float(((uint32_t)b) << 16);
}

__device__ inline void gload_lds16(const void* g, void* l) {
  __builtin_amdgcn_global_load_lds((const __attribute__((address_space(1))) void*)g,
                                   (__attribute__((address_space(3))) void*)l, 16, 0, 0);
}

// ---------------- graph prep ----------------

__global__ void deg_count_kernel(const int* __restrict__ ei, int* __restrict__ deg, int E) {
  int e = blockIdx.x * 256 + threadIdx.x;
  if (e < E) atomicAdd(&deg[ei[E + e]], 1);
}

__global__ void scan_kernel(const int* __restrict__ deg, int* __restrict__ rowptr,
                            int* __restrict__ cursor, int n) {
  __shared__ int wsum[16];
  int t = threadIdx.x;
  int chunk = (n + 1023) >> 10;
  int lo = min(t * chunk, n), hi = min(lo + chunk, n);
  int s = 0;
  for (int i = lo; i < hi; ++i) s += deg[i];
  int lane = t & 63, w = t >> 6;
  int v = s;
#pragma unroll
  for (int off = 1; off < 64; off <<= 1) {
    int u = __shfl_up(v, off);
    if (lane >= off) v += u;
  }
  if (lane == 63) wsum[w] = v;
  __syncthreads();
  if (t == 0) {
    int acc = 0;
#pragma unroll
    for (int i = 0; i < 16; ++i) { int x = wsum[i]; wsum[i] = acc; acc += x; }
  }
  __syncthreads();
  int excl = v - s + wsum[w];
  for (int i = lo; i < hi; ++i) {
    rowptr[i] = excl; cursor[i] = excl; excl += deg[i];
  }
  if (t == 1023) rowptr[n] = excl;
}

__global__ void scatter_kernel(const int* __restrict__ ei, int* __restrict__ cursor,
                               int* __restrict__ csr_src, int* __restrict__ csr_eid, int E) {
  int e = blockIdx.x * 256 + threadIdx.x;
  if (e >= E) return;
  int d = ei[E + e];
  int pos = atomicAdd(&cursor[d], 1);
  csr_src[pos] = ei[e];
  csr_eid[pos] = e;
}

__global__ void permute_ea_kernel(const int* __restrict__ csr_eid,
                                  const float* __restrict__ edge_attr,
                                  float* __restrict__ ea_csr, int E) {
  int gid = blockIdx.x * 256 + threadIdx.x;
  if (gid >= E * 8) return;
  int p = gid >> 3, q = gid & 7;
  int e = csr_eid[p];
  ((float4*)ea_csr)[(size_t)p * 8 + q] = ((const float4*)edge_attr)[(size_t)e * 8 + q];
}

// ---------------- conversions ----------------

__global__ void cvt_bf16_kernel(const float* __restrict__ in,
                                unsigned short* __restrict__ out, int n4) {
  int i = blockIdx.x * 256 + threadIdx.x;
  if (i >= n4) return;
  float4 v = ((const float4*)in)[i];
  ushort4 o;
  o.x = f2bf_rn(v.x); o.y = f2bf_rn(v.y); o.z = f2bf_rn(v.z); o.w = f2bf_rn(v.w);
  ((ushort4*)out)[i] = o;
}

__global__ void transpose_both_kernel(const float* __restrict__ W1, unsigned short* __restrict__ Bt1,
                                      const float* __restrict__ W2, unsigned short* __restrict__ Bt2) {
  __shared__ float tile[32][33];
  int by = blockIdx.y;
  const float* W; unsigned short* Bt; int K, bk;
  if (by < 4) { W = W1; Bt = Bt1; K = 128; bk = by * 32; }
  else        { W = W2; Bt = Bt2; K = 1024; bk = (by - 4) * 32; }
  int bn = blockIdx.x * 32;
  int tx = threadIdx.x & 31, ty = threadIdx.x >> 5;
  for (int r = ty; r < 32; r += 8)
    tile[r][tx] = W[(size_t)(bk + r) * 1024 + bn + tx];
  __syncthreads();
  for (int r = ty; r < 32; r += 8)
    Bt[(size_t)(bn + r) * K + bk + tx] = f2bf_rn(tile[tx][r]);
}

__global__ void ve_both_kernel(const float* __restrict__ We1, const float* __restrict__ ae1,
                               const float* __restrict__ We2, const float* __restrict__ ae2,
                               float* __restrict__ Ve) {
  int b = blockIdx.x;
  const float* We = b ? We2 : We1;
  const float* ae = b ? ae2 : ae1;
  int t = threadIdx.x;
  int d = t >> 3, h = t & 7;
  float s = 0.f;
  for (int c = 0; c < 128; ++c) s = fmaf(We[d * 1024 + h * 128 + c], ae[h * 128 + c], s);
  Ve[b * 256 + t] = s;
}

// ---------------- GEMM1: bf16 1-product, full-K staged, one barrier ----------

__global__ __launch_bounds__(256) void gemm1_fullk_kernel(
    const unsigned short* __restrict__ Abf, const unsigned short* __restrict__ Btbf,
    unsigned short* __restrict__ Cbf, float* __restrict__ a_s, float* __restrict__ a_d,
    const float* __restrict__ att_s, const float* __restrict__ att_d, int M) {
  __shared__ __align__(16) unsigned short lds[4 * 8192];  // 64KB
  __shared__ float redS[128][2];
  __shared__ float redD[128][2];
  const int t = threadIdx.x;
  const int lane = t & 63;
  const int wid = t >> 6;
  const int wr = wid >> 1, wc = wid & 1;
  const int m0 = blockIdx.y * 128;
  const int n0 = blockIdx.x * 128;
  const int hb = blockIdx.x;
  const int srow = lane >> 2;
  const int sg = lane & 3;

#pragma unroll
  for (int s = 0; s < 4; ++s) {
    unsigned short* L = lds + s * 8192;
    int k0 = s * 32;
#pragma unroll
    for (int q = 0; q < 2; ++q) {
      int rb = wid * 32 + q * 16;
      int row = rb + srow;
      int gsrc = sg ^ ((row >> 1) & 3);
      size_t ga = (size_t)(m0 + row) * 128 + k0 + gsrc * 8;
      size_t gb = (size_t)(n0 + row) * 128 + k0 + gsrc * 8;
      gload_lds16(Abf + ga, L + rb * 32);
      gload_lds16(Btbf + gb, L + 4096 + rb * 32);
    }
  }
  __syncthreads();

  int offa[4], offb[4];
#pragma unroll
  for (int i = 0; i < 4; ++i) {
    int rowa = wr * 64 + i * 16 + (lane & 15);
    offa[i] = rowa * 32 + (((lane >> 4) ^ ((rowa >> 1) & 3)) * 8);
    int rowb = wc * 64 + i * 16 + (lane & 15);
    offb[i] = rowb * 32 + (((lane >> 4) ^ ((rowb >> 1) & 3)) * 8);
  }

  f32x4 acc[4][4] = {};
#pragma unroll
  for (int s = 0; s < 4; ++s) {
    unsigned short* L = lds + s * 8192;
    bf16x8 ah[4];
#pragma unroll
    for (int i = 0; i < 4; ++i) ah[i] = *(const bf16x8*)(L + offa[i]);
#pragma unroll
    for (int j = 0; j < 4; ++j) {
      bf16x8 bh = *(const bf16x8*)(L + 4096 + offb[j]);
#pragma unroll
      for (int i = 0; i < 4; ++i)
        acc[i][j] = __builtin_amdgcn_mfma_f32_16x16x32_bf16(ah[i], bh, acc[i][j], 0, 0, 0);
    }
  }

  float as_v[4], ad_v[4];
#pragma unroll
  for (int j = 0; j < 4; ++j) {
    int c = n0 + wc * 64 + j * 16 + (lane & 15);
    as_v[j] = att_s[c];
    ad_v[j] = att_d[c];
  }
#pragma unroll
  for (int i = 0; i < 4; ++i) {
#pragma unroll
    for (int r = 0; r < 4; ++r) {
      float sA = 0.f, sD = 0.f;
#pragma unroll
      for (int j = 0; j < 4; ++j) {
        sA = fmaf(acc[i][j][r], as_v[j], sA);
        sD = fmaf(acc[i][j][r], ad_v[j], sD);
      }
#pragma unroll
      for (int mask = 1; mask <= 8; mask <<= 1) {
        sA += __shfl_xor(sA, mask);
        sD += __shfl_xor(sD, mask);
      }
      if ((lane & 15) == 0) {
        int ml = wr * 64 + i * 16 + (lane >> 4) * 4 + r;
        redS[ml][wc] = sA;
        redD[ml][wc] = sD;
      }
      int m = m0 + wr * 64 + i * 16 + (lane >> 4) * 4 + r;
      if (m < M) {
#pragma unroll
        for (int j = 0; j < 4; ++j) {
          int n = n0 + wc * 64 + j * 16 + (lane & 15);
          Cbf[(size_t)m * 1024 + n] = f2bf_rn(acc[i][j][r]);
        }
      }
    }
  }
  __syncthreads();
  if (t < 128) {
    int m = m0 + t;
    if (m < M) {
      a_s[(size_t)m * 8 + hb] = redS[t][0] + redS[t][1];
      a_d[(size_t)m * 8 + hb] = redD[t][0] + redD[t][1];
    }
  }
}

// ---------------- GEMM2: in-block split-K, 8 waves -----------------
// Wave group kb = wid>>2 handles K-half kb (BK=32 dbuf, 32KB per group).
// 16 block barriers. Combine: group0 -> LDS f32, group1 adds + epilogue.

__global__ __launch_bounds__(512) void gemm2_dbuf_kernel(
    const unsigned short* __restrict__ Abf, const unsigned short* __restrict__ Btbf,
    unsigned short* __restrict__ Cbf, float* __restrict__ a_s, float* __restrict__ a_d,
    const float* __restrict__ att_s, const float* __restrict__ att_d, int M, int K) {
  __shared__ __align__(16) unsigned short lds[2 * 16384];  // 2 groups x 32KB
  __shared__ float redS[128][2];
  __shared__ float redD[128][2];
  const int t = threadIdx.x;
  const int lane = t & 63;
  const int wid = t >> 6;          // 0..7
  const int kb = wid >> 2;         // K-half group
  const int wq = wid & 3;          // quadrant within group
  const int wr = wq >> 1, wc = wq & 1;
  const int m0 = blockIdx.y * 128;
  const int n0 = blockIdx.x * 128;
  const int hb = blockIdx.x;
  const int srow = lane >> 2;
  const int sg = lane & 3;
  const int kbase = kb * (K >> 1);
  const int nk = K >> 6;           // steps per half (BK=32): 16

  auto stage = [&](int b, int k) {
    unsigned short* L = lds + kb * 16384 + b * 8192;
    int k0 = kbase + k * 32;
#pragma unroll
    for (int q = 0; q < 2; ++q) {
      int rb = wq * 32 + q * 16;
      int row = rb + srow;
      int gsrc = sg ^ ((row >> 1) & 3);
      size_t ga = (size_t)(m0 + row) * K + k0 + gsrc * 8;
      size_t gb = (size_t)(n0 + row) * K + k0 + gsrc * 8;
      gload_lds16(Abf + ga, L + rb * 32);
      gload_lds16(Btbf + gb, L + 4096 + rb * 32);
    }
  };

  int offa[4], offb[4];
#pragma unroll
  for (int i = 0; i < 4; ++i) {
    int rowa = wr * 64 + i * 16 + (lane & 15);
    offa[i] = rowa * 32 + (((lane >> 4) ^ ((rowa >> 1) & 3)) * 8);
    int rowb = wc * 64 + i * 16 + (lane & 15);
    offb[i] = rowb * 32 + (((lane >> 4) ^ ((rowb >> 1) & 3)) * 8);
  }

  f32x4 acc[4][4] = {};
  stage(0, 0);
  __syncthreads();

  for (int k = 0; k < nk; ++k) {
    if (k + 1 < nk) stage((k + 1) & 1, k + 1);
    unsigned short* L = lds + kb * 16384 + (k & 1) * 8192;
    bf16x8 ah[4], bh[4];
#pragma unroll
    for (int i = 0; i < 4; ++i) ah[i] = *(const bf16x8*)(L + offa[i]);
#pragma unroll
    for (int j = 0; j < 4; ++j) bh[j] = *(const bf16x8*)(L + 4096 + offb[j]);
#pragma unroll
    for (int j = 0; j < 4; ++j)
#pragma unroll
      for (int i = 0; i < 4; ++i)
        acc[i][j] = __builtin_amdgcn_mfma_f32_16x16x32_bf16(ah[i], bh[j], acc[i][j], 0, 0, 0);
    __syncthreads();
  }

  // combine: group 0 dumps acc into the dead staging LDS; group 1 adds.
  float* cmb = (float*)lds;  // 64KB = 4 quadrants x 64 lanes x 64 f32
  if (kb == 0) {
    float* dst = cmb + wq * 4096 + lane * 64;
#pragma unroll
    for (int i = 0; i < 4; ++i)
#pragma unroll
      for (int j = 0; j < 4; ++j)
        *(f32x4*)(dst + (i * 4 + j) * 4) = acc[i][j];
  }
  __syncthreads();
  if (kb == 1) {
    const float* src = cmb + wq * 4096 + lane * 64;
#pragma unroll
    for (int i = 0; i < 4; ++i)
#pragma unroll
      for (int j = 0; j < 4; ++j) {
        f32x4 p = *(const f32x4*)(src + (i * 4 + j) * 4);
        acc[i][j] += p;
      }

    float as_v[4], ad_v[4];
#pragma unroll
    for (int j = 0; j < 4; ++j) {
      int c = n0 + wc * 64 + j * 16 + (lane & 15);
      as_v[j] = att_s[c];
      ad_v[j] = att_d[c];
    }
#pragma unroll
    for (int i = 0; i < 4; ++i) {
#pragma unroll
      for (int r = 0; r < 4; ++r) {
        float sA = 0.f, sD = 0.f;
#pragma unroll
        for (int j = 0; j < 4; ++j) {
          sA = fmaf(acc[i][j][r], as_v[j], sA);
          sD = fmaf(acc[i][j][r], ad_v[j], sD);
        }
#pragma unroll
        for (int mask = 1; mask <= 8; mask <<= 1) {
          sA += __shfl_xor(sA, mask);
          sD += __shfl_xor(sD, mask);
        }
        if ((lane & 15) == 0) {
          int ml = wr * 64 + i * 16 + (lane >> 4) * 4 + r;
          redS[ml][wc] = sA;
          redD[ml][wc] = sD;
        }
        int m = m0 + wr * 64 + i * 16 + (lane >> 4) * 4 + r;
        if (m < M) {
#pragma unroll
          for (int j = 0; j < 4; ++j) {
            int n = n0 + wc * 64 + j * 16 + (lane & 15);
            Cbf[(size_t)m * 1024 + n] = f2bf_rn(acc[i][j][r]);
          }
        }
      }
    }
  }
  __syncthreads();
  if (t < 128) {
    int m = m0 + t;
    if (m < M) {
      a_s[(size_t)m * 8 + hb] = redS[t][0] + redS[t][1];
      a_d[(size_t)m * 8 + hb] = redD[t][0] + redD[t][1];
    }
  }
}

// ---------------- fused per-node edge-alpha + softmax ----------------

__global__ __launch_bounds__(256) void alpha_sm_kernel(
    const int* __restrict__ rowptr, const int* __restrict__ csr_src,
    const float* __restrict__ ea_csr,
    const float* __restrict__ a_s, const float* __restrict__ a_d,
    const float* __restrict__ Ve,
    float* __restrict__ alpha_t, float* __restrict__ self_t, int N, int E) {
  __shared__ float sVe[EDD][8];
  int t = threadIdx.x;
  sVe[t >> 3][t & 7] = Ve[t];
  __syncthreads();
  int n = blockIdx.x * 4 + (t >> 6);
  if (n >= N) return;
  int lane = t & 63;
  int e8 = lane >> 3, h = lane & 7;
  int r0 = rowptr[n], deg = rowptr[n + 1] - r0;
  float adn = a_d[(size_t)n * 8 + h];
  float m = -1e30f, s = 0.f, aesum = 0.f;
  for (int i = e8; i < deg; i += 8) {
    int p = r0 + i;
    int src = csr_src[p];
    const float4* ea4 = (const float4*)(ea_csr + (size_t)p * EDD);
    float ae = 0.f;
#pragma unroll
    for (int k = 0; k < 8; ++k) {
      float4 v = ea4[k];
      ae = fmaf(v.x, sVe[k * 4 + 0][h], ae);
      ae = fmaf(v.y, sVe[k * 4 + 1][h], ae);
      ae = fmaf(v.z, sVe[k * 4 + 2][h], ae);
      ae = fmaf(v.w, sVe[k * 4 + 3][h], ae);
    }
    aesum += ae;
    float a = a_s[(size_t)src * 8 + h] + adn + ae;
    a = (a > 0.f) ? a : 0.2f * a;
    alpha_t[(size_t)h * E + p] = a;
    if (a <= m) {
      s += __expf(a - m);
    } else {
      s = s * __expf(m - a) + 1.f;
      m = a;
    }
  }
#pragma unroll
  for (int mask = 8; mask <= 32; mask <<= 1) {
    float mo = __shfl_xor(m, mask);
    float so = __shfl_xor(s, mask);
    aesum += __shfl_xor(aesum, mask);
    float mn = fmaxf(m, mo);
    s = s * __expf(m - mn) + so * __expf(mo - mn);
    m = mn;
  }
  float aeself = aesum / fmaxf((float)deg, 1.f);
  float aself = a_s[(size_t)n * 8 + h] + adn + aeself;
  aself = (aself > 0.f) ? aself : 0.2f * aself;
  float mn = fmaxf(m, aself);
  s = s * __expf(m - mn) + __expf(aself - mn);
  float inv = 1.f / (s + 1e-16f);
  if (e8 == 0) self_t[(size_t)h * N + n] = __expf(aself - mn) * inv;
  for (int i = e8; i < deg; i += 8) {
    size_t p = (size_t)h * E + r0 + i;
    alpha_t[p] = __expf(alpha_t[p] - mn) * inv;
  }
}

// ---------------- head-partitioned gather: LDS-staged idx/weights ------------

template <int RELU_BIAS>
__global__ __launch_bounds__(256) void agg_gather_h_kernel(
    const unsigned short* __restrict__ xbf, const float* __restrict__ alpha_t,
    const float* __restrict__ self_t, const int* __restrict__ rowptr,
    const int* __restrict__ csr_src, const float* __restrict__ bias,
    unsigned short* __restrict__ obf, int N, int E) {
  __shared__ int ls_idx[512];
  __shared__ float ls_w[512];
  const int h = blockIdx.x & 7;
  const int g = blockIdx.x >> 3;
  const int t = threadIdx.x;
  const int nb = g * 16;
  const int n = nb + (t >> 4);
  const int sub = t & 15;
  const bool live = (n < N);
  const int r_start = rowptr[nb];
  const int r_end = rowptr[min(nb + 16, N)];
  int r0 = 0, r1 = 0;
  if (live) { r0 = rowptr[n]; r1 = rowptr[n + 1]; }
  const float* __restrict__ pw = alpha_t + (size_t)h * E;
  const size_t cb = (size_t)h * 128 + sub * 8;
  float acc[8] = {0.f, 0.f, 0.f, 0.f, 0.f, 0.f, 0.f, 0.f};
  if (live) {
    float ws = self_t[(size_t)h * N + n];
    u16x8 v = *(const u16x8*)(xbf + (size_t)n * 1024 + cb);
#pragma unroll
    for (int k = 0; k < 8; ++k) acc[k] = ws * bf2f(v[k]);
  }
  for (int base = r_start; base < r_end; base += 512) {
    int cnt = min(512, r_end - base);
    for (int i = t; i < cnt; i += 256) {
      ls_idx[i] = csr_src[base + i];
      ls_w[i] = pw[base + i];
    }
    __syncthreads();
    if (live) {
      int lo = max(r0, base), hi = min(r1, base + cnt);
      int p = lo;
      for (; p + 4 <= hi; p += 4) {
        int q0 = p - base;
        float w0 = ls_w[q0], w1 = ls_w[q0 + 1], w2 = ls_w[q0 + 2], w3 = ls_w[q0 + 3];
        int s0 = ls_idx[q0], s1 = ls_idx[q0 + 1], s2 = ls_idx[q0 + 2], s3 = ls_idx[q0 + 3];
        u16x8 v0 = *(const u16x8*)(xbf + (size_t)s0 * 1024 + cb);
        u16x8 v1 = *(const u16x8*)(xbf + (size_t)s1 * 1024 + cb);
        u16x8 v2 = *(const u16x8*)(xbf + (size_t)s2 * 1024 + cb);
        u16x8 v3 = *(const u16x8*)(xbf + (size_t)s3 * 1024 + cb);
#pragma unroll
        for (int k = 0; k < 8; ++k) acc[k] = fmaf(w0, bf2f(v0[k]), acc[k]);
#pragma unroll
        for (int k = 0; k < 8; ++k) acc[k] = fmaf(w1, bf2f(v1[k]), acc[k]);
#pragma unroll
        for (int k = 0; k < 8; ++k) acc[k] = fmaf(w2, bf2f(v2[k]), acc[k]);
#pragma unroll
        for (int k = 0; k < 8; ++k) acc[k] = fmaf(w3, bf2f(v3[k]), acc[k]);
      }
      for (; p < hi; ++p) {
        int q0 = p - base;
        float w0 = ls_w[q0];
        int s0 = ls_idx[q0];
        u16x8 v0 = *(const u16x8*)(xbf + (size_t)s0 * 1024 + cb);
#pragma unroll
        for (int k = 0; k < 8; ++k) acc[k] = fmaf(w0, bf2f(v0[k]), acc[k]);
      }
    }
    __syncthreads();
  }
  if (!live) return;
  u16x8 o;
  if (RELU_BIAS) {
    float4 b0 = *(const float4*)(bias + cb);
    float4 b1v = *(const float4*)(bias + cb + 4);
    float bb[8] = {b0.x, b0.y, b0.z, b0.w, b1v.x, b1v.y, b1v.z, b1v.w};
#pragma unroll
    for (int k = 0; k < 8; ++k) o[k] = f2bf_rn(fmaxf(acc[k] + bb[k], 0.f));
  } else {
#pragma unroll
    for (int k = 0; k < 8; ++k) o[k] = f2bf_rn(acc[k]);
  }
  *(u16x8*)(obf + (size_t)n * 1024 + cb) = o;
}

// ---------------- layer-2 head mean + bias ----------------

__global__ void head_reduce_kernel(const unsigned short* __restrict__ xpart,
                                   const float* __restrict__ b2,
                                   float* __restrict__ outp, int N) {
  int gid = blockIdx.x * 256 + threadIdx.x;
  if (gid >= N * 32) return;
  int n = gid >> 5, q = gid & 31;
  float sx = 0.f, sy = 0.f, sz = 0.f, sw = 0.f;
#pragma unroll
  for (int h = 0; h < 8; ++h) {
    ushort4 v = *(const ushort4*)(xpart + (size_t)n * 1024 + h * 128 + q * 4);
    sx += bf2f(v.x); sy += bf2f(v.y); sz += bf2f(v.z); sw += bf2f(v.w);
  }
  float4 b = ((const float4*)b2)[q];
  float4 o;
  o.x = sx * 0.125f + b.x;
  o.y = sy * 0.125f + b.y;
  o.z = sz * 0.125f + b.z;
  o.w = sw * 0.125f + b.w;
  ((float4*)outp)[(size_t)n * 32 + q] = o;
}

// ---------------- launch ----------------

extern "C" void kernel_launch(void* const* d_in, const int* in_sizes, int n_in,
                              void* d_out, int out_size, void* d_ws, size_t ws_size,
                              hipStream_t stream) {
  const float* x        = (const float*)d_in[0];
  const int*   ei       = (const int*)d_in[1];
  const float* edge_attr= (const float*)d_in[2];
  const float* W1       = (const float*)d_in[3];
  const float* We1      = (const float*)d_in[4];
  const float* as1      = (const float*)d_in[5];
  const float* ad1      = (const float*)d_in[6];
  const float* ae1      = (const float*)d_in[7];
  const float* b1       = (const float*)d_in[8];
  const float* W2       = (const float*)d_in[9];
  const float* We2      = (const float*)d_in[10];
  const float* as2      = (const float*)d_in[11];
  const float* ad2      = (const float*)d_in[12];
  const float* ae2      = (const float*)d_in[13];
  const float* b2       = (const float*)d_in[14];
  float* out = (float*)d_out;

  const int N = in_sizes[0] / 128;   // 10000 nodes
  const int E = in_sizes[2] / EDD;   // 160000 edges
  const int Mpad = ((N + 127) / 128) * 128;  // 10112

  char* ws = (char*)d_ws;
  size_t off = 0;
  auto alloc = [&](size_t bytes) -> void* {
    void* p = ws + off;
    off = (off + bytes + 255) & ~(size_t)255;
    return p;
  };
  int*   deg       = (int*)alloc((size_t)N * 4);
  int*   rowptr    = (int*)alloc((size_t)(N + 1) * 4);
  int*   cursor    = (int*)alloc((size_t)N * 4);
  int*   csr_src   = (int*)alloc((size_t)E * 4);
  int*   csr_eid   = (int*)alloc((size_t)E * 4);
  float* ea_csr    = (float*)alloc((size_t)E * EDD * 4);
  float* a_s       = (float*)alloc((size_t)N * 8 * 4);
  float* a_d       = (float*)alloc((size_t)N * 8 * 4);
  float* Ve        = (float*)alloc(512 * 4);
  float* alpha_t   = (float*)alloc((size_t)E * 8 * 4);
  float* self_t    = (float*)alloc((size_t)N * 8 * 4);
  unsigned short* xh1bf = (unsigned short*)alloc((size_t)N * 1024 * 2);
  unsigned short* xh2bf = (unsigned short*)alloc((size_t)N * 1024 * 2);
  unsigned short* xpart = (unsigned short*)alloc((size_t)N * 1024 * 2);
  unsigned short* xbf   = (unsigned short*)alloc((size_t)Mpad * 128 * 2);
  unsigned short* Bt1   = (unsigned short*)alloc((size_t)1024 * 128 * 2);
  unsigned short* Bt2   = (unsigned short*)alloc((size_t)1024 * 1024 * 2);
  unsigned short* h1bf  = (unsigned short*)alloc((size_t)Mpad * 1024 * 2);
  (void)ws_size; (void)n_in; (void)out_size;

  hipMemsetAsync(deg, 0, (size_t)N * 4, stream);

  int gE = (E + 255) / 256;
  deg_count_kernel<<<gE, 256, 0, stream>>>(ei, deg, E);
  scan_kernel<<<1, 1024, 0, stream>>>(deg, rowptr, cursor, N);
  scatter_kernel<<<gE, 256, 0, stream>>>(ei, cursor, csr_src, csr_eid, E);
  permute_ea_kernel<<<(E * 8 + 255) / 256, 256, 0, stream>>>(csr_eid, edge_attr, ea_csr, E);

  cvt_bf16_kernel<<<(N * 128 / 4 + 255) / 256, 256, 0, stream>>>(x, xbf, N * 128 / 4);
  transpose_both_kernel<<<dim3(32, 36), 256, 0, stream>>>(W1, Bt1, W2, Bt2);
  ve_both_kernel<<<2, 256, 0, stream>>>(We1, ae1, We2, ae2, Ve);

  dim3 ggrid(8, Mpad / 128);
  int gSM = (N + 3) / 4;
  int gAG = 8 * ((N + 15) / 16);

  // ---- layer 1 ----
  gemm1_fullk_kernel<<<ggrid, 256, 0, stream>>>(xbf, Bt1, xh1bf, a_s, a_d, as1, ad1, N);
  alpha_sm_kernel<<<gSM, 256, 0, stream>>>(rowptr, csr_src, ea_csr, a_s, a_d, Ve,
                                           alpha_t, self_t, N, E);
  agg_gather_h_kernel<1><<<gAG, 256, 0, stream>>>(xh1bf, alpha_t, self_t, rowptr, csr_src,
                                                  b1, h1bf, N, E);

  // ---- layer 2 ----
  gemm2_dbuf_kernel<<<ggrid, 512, 0, stream>>>(h1bf, Bt2, xh2bf, a_s, a_d, as2, ad2, N, 1024);
  alpha_sm_kernel<<<gSM, 256, 0, stream>>>(rowptr, csr_src, ea_csr, a_s, a_d, Ve + 256,
                                           alpha_t, self_t, N, E);
  agg_gather_h_kernel<0><<<gAG, 256, 0, stream>>>(xh2bf, alpha_t, self_t, rowptr, csr_src,
                                                  nullptr, xpart, N, E);
  head_reduce_kernel<<<(N * 32 + 255) / 256, 256, 0, stream>>>(xpart, b2, out, N);
}

// Round 17
// 210.692 us; speedup vs baseline: 1.1427x; 1.1427x over previous
//
#include <hip/hip_runtime.h>
#include <hip/hip_bf16.h>
#include <cstdint>
#include <cstddef>

// TwoLayerGAT on MI355X — round 17: EXACT revert to round 14 (measured best,
// 211us). gemm2 experiments (B-in-reg r11, BK=64 r15, split-K r16) all
// regressed; the 2-phase BK=32 dbuf is the structure's local optimum.

#define EDD 32

typedef __attribute__((ext_vector_type(4))) float f32x4;
typedef __attribute__((ext_vector_type(8))) short bf16x8;
typedef __attribute__((ext_vector_type(8))) unsigned short u16x8;

__device__ inline unsigned short f2bf_rn(float f) {
  uint32_t u = __float_as_uint(f);
  return (unsigned short)((u + 0x7FFFu + ((u >> 16) & 1u)) >> 16);
}

__device__ inline float bf2f(unsigned short b) {
  return __uint_as_float(((uint32_t)b) << 16);
}

__device__ inline void gload_lds16(const void* g, void* l) {
  __builtin_amdgcn_global_load_lds((const __attribute__((address_space(1))) void*)g,
                                   (__attribute__((address_space(3))) void*)l, 16, 0, 0);
}

// ---------------- graph prep ----------------

__global__ void deg_count_kernel(const int* __restrict__ ei, int* __restrict__ deg, int E) {
  int e = blockIdx.x * 256 + threadIdx.x;
  if (e < E) atomicAdd(&deg[ei[E + e]], 1);
}

__global__ void scan_kernel(const int* __restrict__ deg, int* __restrict__ rowptr,
                            int* __restrict__ cursor, int n) {
  __shared__ int wsum[16];
  int t = threadIdx.x;
  int chunk = (n + 1023) >> 10;
  int lo = min(t * chunk, n), hi = min(lo + chunk, n);
  int s = 0;
  for (int i = lo; i < hi; ++i) s += deg[i];
  int lane = t & 63, w = t >> 6;
  int v = s;
#pragma unroll
  for (int off = 1; off < 64; off <<= 1) {
    int u = __shfl_up(v, off);
    if (lane >= off) v += u;
  }
  if (lane == 63) wsum[w] = v;
  __syncthreads();
  if (t == 0) {
    int acc = 0;
#pragma unroll
    for (int i = 0; i < 16; ++i) { int x = wsum[i]; wsum[i] = acc; acc += x; }
  }
  __syncthreads();
  int excl = v - s + wsum[w];
  for (int i = lo; i < hi; ++i) {
    rowptr[i] = excl; cursor[i] = excl; excl += deg[i];
  }
  if (t == 1023) rowptr[n] = excl;
}

__global__ void scatter_kernel(const int* __restrict__ ei, int* __restrict__ cursor,
                               int* __restrict__ csr_src, int* __restrict__ csr_eid, int E) {
  int e = blockIdx.x * 256 + threadIdx.x;
  if (e >= E) return;
  int d = ei[E + e];
  int pos = atomicAdd(&cursor[d], 1);
  csr_src[pos] = ei[e];
  csr_eid[pos] = e;
}

__global__ void permute_ea_kernel(const int* __restrict__ csr_eid,
                                  const float* __restrict__ edge_attr,
                                  float* __restrict__ ea_csr, int E) {
  int gid = blockIdx.x * 256 + threadIdx.x;
  if (gid >= E * 8) return;
  int p = gid >> 3, q = gid & 7;
  int e = csr_eid[p];
  ((float4*)ea_csr)[(size_t)p * 8 + q] = ((const float4*)edge_attr)[(size_t)e * 8 + q];
}

// ---------------- conversions ----------------

__global__ void cvt_bf16_kernel(const float* __restrict__ in,
                                unsigned short* __restrict__ out, int n4) {
  int i = blockIdx.x * 256 + threadIdx.x;
  if (i >= n4) return;
  float4 v = ((const float4*)in)[i];
  ushort4 o;
  o.x = f2bf_rn(v.x); o.y = f2bf_rn(v.y); o.z = f2bf_rn(v.z); o.w = f2bf_rn(v.w);
  ((ushort4*)out)[i] = o;
}

__global__ void transpose_both_kernel(const float* __restrict__ W1, unsigned short* __restrict__ Bt1,
                                      const float* __restrict__ W2, unsigned short* __restrict__ Bt2) {
  __shared__ float tile[32][33];
  int by = blockIdx.y;
  const float* W; unsigned short* Bt; int K, bk;
  if (by < 4) { W = W1; Bt = Bt1; K = 128; bk = by * 32; }
  else        { W = W2; Bt = Bt2; K = 1024; bk = (by - 4) * 32; }
  int bn = blockIdx.x * 32;
  int tx = threadIdx.x & 31, ty = threadIdx.x >> 5;
  for (int r = ty; r < 32; r += 8)
    tile[r][tx] = W[(size_t)(bk + r) * 1024 + bn + tx];
  __syncthreads();
  for (int r = ty; r < 32; r += 8)
    Bt[(size_t)(bn + r) * K + bk + tx] = f2bf_rn(tile[tx][r]);
}

__global__ void ve_both_kernel(const float* __restrict__ We1, const float* __restrict__ ae1,
                               const float* __restrict__ We2, const float* __restrict__ ae2,
                               float* __restrict__ Ve) {
  int b = blockIdx.x;
  const float* We = b ? We2 : We1;
  const float* ae = b ? ae2 : ae1;
  int t = threadIdx.x;
  int d = t >> 3, h = t & 7;
  float s = 0.f;
  for (int c = 0; c < 128; ++c) s = fmaf(We[d * 1024 + h * 128 + c], ae[h * 128 + c], s);
  Ve[b * 256 + t] = s;
}

// ---------------- GEMM1: bf16 1-product, full-K staged, one barrier ----------

__global__ __launch_bounds__(256) void gemm1_fullk_kernel(
    const unsigned short* __restrict__ Abf, const unsigned short* __restrict__ Btbf,
    unsigned short* __restrict__ Cbf, float* __restrict__ a_s, float* __restrict__ a_d,
    const float* __restrict__ att_s, const float* __restrict__ att_d, int M) {
  __shared__ __align__(16) unsigned short lds[4 * 8192];  // 64KB
  __shared__ float redS[128][2];
  __shared__ float redD[128][2];
  const int t = threadIdx.x;
  const int lane = t & 63;
  const int wid = t >> 6;
  const int wr = wid >> 1, wc = wid & 1;
  const int m0 = blockIdx.y * 128;
  const int n0 = blockIdx.x * 128;
  const int hb = blockIdx.x;
  const int srow = lane >> 2;
  const int sg = lane & 3;

#pragma unroll
  for (int s = 0; s < 4; ++s) {
    unsigned short* L = lds + s * 8192;
    int k0 = s * 32;
#pragma unroll
    for (int q = 0; q < 2; ++q) {
      int rb = wid * 32 + q * 16;
      int row = rb + srow;
      int gsrc = sg ^ ((row >> 1) & 3);
      size_t ga = (size_t)(m0 + row) * 128 + k0 + gsrc * 8;
      size_t gb = (size_t)(n0 + row) * 128 + k0 + gsrc * 8;
      gload_lds16(Abf + ga, L + rb * 32);
      gload_lds16(Btbf + gb, L + 4096 + rb * 32);
    }
  }
  __syncthreads();

  int offa[4], offb[4];
#pragma unroll
  for (int i = 0; i < 4; ++i) {
    int rowa = wr * 64 + i * 16 + (lane & 15);
    offa[i] = rowa * 32 + (((lane >> 4) ^ ((rowa >> 1) & 3)) * 8);
    int rowb = wc * 64 + i * 16 + (lane & 15);
    offb[i] = rowb * 32 + (((lane >> 4) ^ ((rowb >> 1) & 3)) * 8);
  }

  f32x4 acc[4][4] = {};
#pragma unroll
  for (int s = 0; s < 4; ++s) {
    unsigned short* L = lds + s * 8192;
    bf16x8 ah[4];
#pragma unroll
    for (int i = 0; i < 4; ++i) ah[i] = *(const bf16x8*)(L + offa[i]);
#pragma unroll
    for (int j = 0; j < 4; ++j) {
      bf16x8 bh = *(const bf16x8*)(L + 4096 + offb[j]);
#pragma unroll
      for (int i = 0; i < 4; ++i)
        acc[i][j] = __builtin_amdgcn_mfma_f32_16x16x32_bf16(ah[i], bh, acc[i][j], 0, 0, 0);
    }
  }

  float as_v[4], ad_v[4];
#pragma unroll
  for (int j = 0; j < 4; ++j) {
    int c = n0 + wc * 64 + j * 16 + (lane & 15);
    as_v[j] = att_s[c];
    ad_v[j] = att_d[c];
  }
#pragma unroll
  for (int i = 0; i < 4; ++i) {
#pragma unroll
    for (int r = 0; r < 4; ++r) {
      float sA = 0.f, sD = 0.f;
#pragma unroll
      for (int j = 0; j < 4; ++j) {
        sA = fmaf(acc[i][j][r], as_v[j], sA);
        sD = fmaf(acc[i][j][r], ad_v[j], sD);
      }
#pragma unroll
      for (int mask = 1; mask <= 8; mask <<= 1) {
        sA += __shfl_xor(sA, mask);
        sD += __shfl_xor(sD, mask);
      }
      if ((lane & 15) == 0) {
        int ml = wr * 64 + i * 16 + (lane >> 4) * 4 + r;
        redS[ml][wc] = sA;
        redD[ml][wc] = sD;
      }
      int m = m0 + wr * 64 + i * 16 + (lane >> 4) * 4 + r;
      if (m < M) {
#pragma unroll
        for (int j = 0; j < 4; ++j) {
          int n = n0 + wc * 64 + j * 16 + (lane & 15);
          Cbf[(size_t)m * 1024 + n] = f2bf_rn(acc[i][j][r]);
        }
      }
    }
  }
  __syncthreads();
  if (t < 128) {
    int m = m0 + t;
    if (m < M) {
      a_s[(size_t)m * 8 + hb] = redS[t][0] + redS[t][1];
      a_d[(size_t)m * 8 + hb] = redD[t][0] + redD[t][1];
    }
  }
}

// ---------------- GEMM2: bf16 1-product, 2-phase double-buffer ---------------

__global__ __launch_bounds__(256) void gemm2_dbuf_kernel(
    const unsigned short* __restrict__ Abf, const unsigned short* __restrict__ Btbf,
    unsigned short* __restrict__ Cbf, float* __restrict__ a_s, float* __restrict__ a_d,
    const float* __restrict__ att_s, const float* __restrict__ att_d, int M, int K) {
  __shared__ __align__(16) unsigned short lds[2 * 8192];  // 32KB
  __shared__ float redS[128][2];
  __shared__ float redD[128][2];
  const int t = threadIdx.x;
  const int lane = t & 63;
  const int wid = t >> 6;
  const int wr = wid >> 1, wc = wid & 1;
  const int m0 = blockIdx.y * 128;
  const int n0 = blockIdx.x * 128;
  const int hb = blockIdx.x;
  const int srow = lane >> 2;
  const int sg = lane & 3;
  const int nk = K >> 5;

  auto stage = [&](int b, int k) {
    unsigned short* L = lds + b * 8192;
    int k0 = k * 32;
#pragma unroll
    for (int q = 0; q < 2; ++q) {
      int rb = wid * 32 + q * 16;
      int row = rb + srow;
      int gsrc = sg ^ ((row >> 1) & 3);
      size_t ga = (size_t)(m0 + row) * K + k0 + gsrc * 8;
      size_t gb = (size_t)(n0 + row) * K + k0 + gsrc * 8;
      gload_lds16(Abf + ga, L + rb * 32);
      gload_lds16(Btbf + gb, L + 4096 + rb * 32);
    }
  };

  int offa[4], offb[4];
#pragma unroll
  for (int i = 0; i < 4; ++i) {
    int rowa = wr * 64 + i * 16 + (lane & 15);
    offa[i] = rowa * 32 + (((lane >> 4) ^ ((rowa >> 1) & 3)) * 8);
    int rowb = wc * 64 + i * 16 + (lane & 15);
    offb[i] = rowb * 32 + (((lane >> 4) ^ ((rowb >> 1) & 3)) * 8);
  }

  f32x4 acc[4][4] = {};
  stage(0, 0);
  __syncthreads();

  for (int k = 0; k < nk; ++k) {
    if (k + 1 < nk) stage((k + 1) & 1, k + 1);
    unsigned short* L = lds + (k & 1) * 8192;
    bf16x8 ah[4], bh[4];
#pragma unroll
    for (int i = 0; i < 4; ++i) ah[i] = *(const bf16x8*)(L + offa[i]);
#pragma unroll
    for (int j = 0; j < 4; ++j) bh[j] = *(const bf16x8*)(L + 4096 + offb[j]);
#pragma unroll
    for (int j = 0; j < 4; ++j)
#pragma unroll
      for (int i = 0; i < 4; ++i)
        acc[i][j] = __builtin_amdgcn_mfma_f32_16x16x32_bf16(ah[i], bh[j], acc[i][j], 0, 0, 0);
    __syncthreads();
  }

  float as_v[4], ad_v[4];
#pragma unroll
  for (int j = 0; j < 4; ++j) {
    int c = n0 + wc * 64 + j * 16 + (lane & 15);
    as_v[j] = att_s[c];
    ad_v[j] = att_d[c];
  }
#pragma unroll
  for (int i = 0; i < 4; ++i) {
#pragma unroll
    for (int r = 0; r < 4; ++r) {
      float sA = 0.f, sD = 0.f;
#pragma unroll
      for (int j = 0; j < 4; ++j) {
        sA = fmaf(acc[i][j][r], as_v[j], sA);
        sD = fmaf(acc[i][j][r], ad_v[j], sD);
      }
#pragma unroll
      for (int mask = 1; mask <= 8; mask <<= 1) {
        sA += __shfl_xor(sA, mask);
        sD += __shfl_xor(sD, mask);
      }
      if ((lane & 15) == 0) {
        int ml = wr * 64 + i * 16 + (lane >> 4) * 4 + r;
        redS[ml][wc] = sA;
        redD[ml][wc] = sD;
      }
      int m = m0 + wr * 64 + i * 16 + (lane >> 4) * 4 + r;
      if (m < M) {
#pragma unroll
        for (int j = 0; j < 4; ++j) {
          int n = n0 + wc * 64 + j * 16 + (lane & 15);
          Cbf[(size_t)m * 1024 + n] = f2bf_rn(acc[i][j][r]);
        }
      }
    }
  }
  __syncthreads();
  if (t < 128) {
    int m = m0 + t;
    if (m < M) {
      a_s[(size_t)m * 8 + hb] = redS[t][0] + redS[t][1];
      a_d[(size_t)m * 8 + hb] = redD[t][0] + redD[t][1];
    }
  }
}

// ---------------- fused per-node edge-alpha + softmax ----------------

__global__ __launch_bounds__(256) void alpha_sm_kernel(
    const int* __restrict__ rowptr, const int* __restrict__ csr_src,
    const float* __restrict__ ea_csr,
    const float* __restrict__ a_s, const float* __restrict__ a_d,
    const float* __restrict__ Ve,
    float* __restrict__ alpha_t, float* __restrict__ self_t, int N, int E) {
  __shared__ float sVe[EDD][8];
  int t = threadIdx.x;
  sVe[t >> 3][t & 7] = Ve[t];
  __syncthreads();
  int n = blockIdx.x * 4 + (t >> 6);
  if (n >= N) return;
  int lane = t & 63;
  int e8 = lane >> 3, h = lane & 7;
  int r0 = rowptr[n], deg = rowptr[n + 1] - r0;
  float adn = a_d[(size_t)n * 8 + h];
  float m = -1e30f, s = 0.f, aesum = 0.f;
  for (int i = e8; i < deg; i += 8) {
    int p = r0 + i;
    int src = csr_src[p];
    const float4* ea4 = (const float4*)(ea_csr + (size_t)p * EDD);
    float ae = 0.f;
#pragma unroll
    for (int k = 0; k < 8; ++k) {
      float4 v = ea4[k];
      ae = fmaf(v.x, sVe[k * 4 + 0][h], ae);
      ae = fmaf(v.y, sVe[k * 4 + 1][h], ae);
      ae = fmaf(v.z, sVe[k * 4 + 2][h], ae);
      ae = fmaf(v.w, sVe[k * 4 + 3][h], ae);
    }
    aesum += ae;
    float a = a_s[(size_t)src * 8 + h] + adn + ae;
    a = (a > 0.f) ? a : 0.2f * a;
    alpha_t[(size_t)h * E + p] = a;
    if (a <= m) {
      s += __expf(a - m);
    } else {
      s = s * __expf(m - a) + 1.f;
      m = a;
    }
  }
#pragma unroll
  for (int mask = 8; mask <= 32; mask <<= 1) {
    float mo = __shfl_xor(m, mask);
    float so = __shfl_xor(s, mask);
    aesum += __shfl_xor(aesum, mask);
    float mn = fmaxf(m, mo);
    s = s * __expf(m - mn) + so * __expf(mo - mn);
    m = mn;
  }
  float aeself = aesum / fmaxf((float)deg, 1.f);
  float aself = a_s[(size_t)n * 8 + h] + adn + aeself;
  aself = (aself > 0.f) ? aself : 0.2f * aself;
  float mn = fmaxf(m, aself);
  s = s * __expf(m - mn) + __expf(aself - mn);
  float inv = 1.f / (s + 1e-16f);
  if (e8 == 0) self_t[(size_t)h * N + n] = __expf(aself - mn) * inv;
  for (int i = e8; i < deg; i += 8) {
    size_t p = (size_t)h * E + r0 + i;
    alpha_t[p] = __expf(alpha_t[p] - mn) * inv;
  }
}

// ---------------- head-partitioned gather: LDS-staged idx/weights ------------

template <int RELU_BIAS>
__global__ __launch_bounds__(256) void agg_gather_h_kernel(
    const unsigned short* __restrict__ xbf, const float* __restrict__ alpha_t,
    const float* __restrict__ self_t, const int* __restrict__ rowptr,
    const int* __restrict__ csr_src, const float* __restrict__ bias,
    unsigned short* __restrict__ obf, int N, int E) {
  __shared__ int ls_idx[512];
  __shared__ float ls_w[512];
  const int h = blockIdx.x & 7;
  const int g = blockIdx.x >> 3;
  const int t = threadIdx.x;
  const int nb = g * 16;
  const int n = nb + (t >> 4);
  const int sub = t & 15;
  const bool live = (n < N);
  const int r_start = rowptr[nb];
  const int r_end = rowptr[min(nb + 16, N)];
  int r0 = 0, r1 = 0;
  if (live) { r0 = rowptr[n]; r1 = rowptr[n + 1]; }
  const float* __restrict__ pw = alpha_t + (size_t)h * E;
  const size_t cb = (size_t)h * 128 + sub * 8;
  float acc[8] = {0.f, 0.f, 0.f, 0.f, 0.f, 0.f, 0.f, 0.f};
  if (live) {
    float ws = self_t[(size_t)h * N + n];
    u16x8 v = *(const u16x8*)(xbf + (size_t)n * 1024 + cb);
#pragma unroll
    for (int k = 0; k < 8; ++k) acc[k] = ws * bf2f(v[k]);
  }
  for (int base = r_start; base < r_end; base += 512) {
    int cnt = min(512, r_end - base);
    for (int i = t; i < cnt; i += 256) {
      ls_idx[i] = csr_src[base + i];
      ls_w[i] = pw[base + i];
    }
    __syncthreads();
    if (live) {
      int lo = max(r0, base), hi = min(r1, base + cnt);
      int p = lo;
      for (; p + 4 <= hi; p += 4) {
        int q0 = p - base;
        float w0 = ls_w[q0], w1 = ls_w[q0 + 1], w2 = ls_w[q0 + 2], w3 = ls_w[q0 + 3];
        int s0 = ls_idx[q0], s1 = ls_idx[q0 + 1], s2 = ls_idx[q0 + 2], s3 = ls_idx[q0 + 3];
        u16x8 v0 = *(const u16x8*)(xbf + (size_t)s0 * 1024 + cb);
        u16x8 v1 = *(const u16x8*)(xbf + (size_t)s1 * 1024 + cb);
        u16x8 v2 = *(const u16x8*)(xbf + (size_t)s2 * 1024 + cb);
        u16x8 v3 = *(const u16x8*)(xbf + (size_t)s3 * 1024 + cb);
#pragma unroll
        for (int k = 0; k < 8; ++k) acc[k] = fmaf(w0, bf2f(v0[k]), acc[k]);
#pragma unroll
        for (int k = 0; k < 8; ++k) acc[k] = fmaf(w1, bf2f(v1[k]), acc[k]);
#pragma unroll
        for (int k = 0; k < 8; ++k) acc[k] = fmaf(w2, bf2f(v2[k]), acc[k]);
#pragma unroll
        for (int k = 0; k < 8; ++k) acc[k] = fmaf(w3, bf2f(v3[k]), acc[k]);
      }
      for (; p < hi; ++p) {
        int q0 = p - base;
        float w0 = ls_w[q0];
        int s0 = ls_idx[q0];
        u16x8 v0 = *(const u16x8*)(xbf + (size_t)s0 * 1024 + cb);
#pragma unroll
        for (int k = 0; k < 8; ++k) acc[k] = fmaf(w0, bf2f(v0[k]), acc[k]);
      }
    }
    __syncthreads();
  }
  if (!live) return;
  u16x8 o;
  if (RELU_BIAS) {
    float4 b0 = *(const float4*)(bias + cb);
    float4 b1v = *(const float4*)(bias + cb + 4);
    float bb[8] = {b0.x, b0.y, b0.z, b0.w, b1v.x, b1v.y, b1v.z, b1v.w};
#pragma unroll
    for (int k = 0; k < 8; ++k) o[k] = f2bf_rn(fmaxf(acc[k] + bb[k], 0.f));
  } else {
#pragma unroll
    for (int k = 0; k < 8; ++k) o[k] = f2bf_rn(acc[k]);
  }
  *(u16x8*)(obf + (size_t)n * 1024 + cb) = o;
}

// ---------------- layer-2 head mean + bias ----------------

__global__ void head_reduce_kernel(const unsigned short* __restrict__ xpart,
                                   const float* __restrict__ b2,
                                   float* __restrict__ outp, int N) {
  int gid = blockIdx.x * 256 + threadIdx.x;
  if (gid >= N * 32) return;
  int n = gid >> 5, q = gid & 31;
  float sx = 0.f, sy = 0.f, sz = 0.f, sw = 0.f;
#pragma unroll
  for (int h = 0; h < 8; ++h) {
    ushort4 v = *(const ushort4*)(xpart + (size_t)n * 1024 + h * 128 + q * 4);
    sx += bf2f(v.x); sy += bf2f(v.y); sz += bf2f(v.z); sw += bf2f(v.w);
  }
  float4 b = ((const float4*)b2)[q];
  float4 o;
  o.x = sx * 0.125f + b.x;
  o.y = sy * 0.125f + b.y;
  o.z = sz * 0.125f + b.z;
  o.w = sw * 0.125f + b.w;
  ((float4*)outp)[(size_t)n * 32 + q] = o;
}

// ---------------- launch ----------------

extern "C" void kernel_launch(void* const* d_in, const int* in_sizes, int n_in,
                              void* d_out, int out_size, void* d_ws, size_t ws_size,
                              hipStream_t stream) {
  const float* x        = (const float*)d_in[0];
  const int*   ei       = (const int*)d_in[1];
  const float* edge_attr= (const float*)d_in[2];
  const float* W1       = (const float*)d_in[3];
  const float* We1      = (const float*)d_in[4];
  const float* as1      = (const float*)d_in[5];
  const float* ad1      = (const float*)d_in[6];
  const float* ae1      = (const float*)d_in[7];
  const float* b1       = (const float*)d_in[8];
  const float* W2       = (const float*)d_in[9];
  const float* We2      = (const float*)d_in[10];
  const float* as2      = (const float*)d_in[11];
  const float* ad2      = (const float*)d_in[12];
  const float* ae2      = (const float*)d_in[13];
  const float* b2       = (const float*)d_in[14];
  float* out = (float*)d_out;

  const int N = in_sizes[0] / 128;   // 10000 nodes
  const int E = in_sizes[2] / EDD;   // 160000 edges
  const int Mpad = ((N + 127) / 128) * 128;  // 10112

  char* ws = (char*)d_ws;
  size_t off = 0;
  auto alloc = [&](size_t bytes) -> void* {
    void* p = ws + off;
    off = (off + bytes + 255) & ~(size_t)255;
    return p;
  };
  int*   deg       = (int*)alloc((size_t)N * 4);
  int*   rowptr    = (int*)alloc((size_t)(N + 1) * 4);
  int*   cursor    = (int*)alloc((size_t)N * 4);
  int*   csr_src   = (int*)alloc((size_t)E * 4);
  int*   csr_eid   = (int*)alloc((size_t)E * 4);
  float* ea_csr    = (float*)alloc((size_t)E * EDD * 4);
  float* a_s       = (float*)alloc((size_t)N * 8 * 4);
  float* a_d       = (float*)alloc((size_t)N * 8 * 4);
  float* Ve        = (float*)alloc(512 * 4);
  float* alpha_t   = (float*)alloc((size_t)E * 8 * 4);
  float* self_t    = (float*)alloc((size_t)N * 8 * 4);
  unsigned short* xh1bf = (unsigned short*)alloc((size_t)N * 1024 * 2);
  unsigned short* xh2bf = (unsigned short*)alloc((size_t)N * 1024 * 2);
  unsigned short* xpart = (unsigned short*)alloc((size_t)N * 1024 * 2);
  unsigned short* xbf   = (unsigned short*)alloc((size_t)Mpad * 128 * 2);
  unsigned short* Bt1   = (unsigned short*)alloc((size_t)1024 * 128 * 2);
  unsigned short* Bt2   = (unsigned short*)alloc((size_t)1024 * 1024 * 2);
  unsigned short* h1bf  = (unsigned short*)alloc((size_t)Mpad * 1024 * 2);
  (void)ws_size; (void)n_in; (void)out_size;

  hipMemsetAsync(deg, 0, (size_t)N * 4, stream);

  int gE = (E + 255) / 256;
  deg_count_kernel<<<gE, 256, 0, stream>>>(ei, deg, E);
  scan_kernel<<<1, 1024, 0, stream>>>(deg, rowptr, cursor, N);
  scatter_kernel<<<gE, 256, 0, stream>>>(ei, cursor, csr_src, csr_eid, E);
  permute_ea_kernel<<<(E * 8 + 255) / 256, 256, 0, stream>>>(csr_eid, edge_attr, ea_csr, E);

  cvt_bf16_kernel<<<(N * 128 / 4 + 255) / 256, 256, 0, stream>>>(x, xbf, N * 128 / 4);
  transpose_both_kernel<<<dim3(32, 36), 256, 0, stream>>>(W1, Bt1, W2, Bt2);
  ve_both_kernel<<<2, 256, 0, stream>>>(We1, ae1, We2, ae2, Ve);

  dim3 ggrid(8, Mpad / 128);
  int gSM = (N + 3) / 4;
  int gAG = 8 * ((N + 15) / 16);

  // ---- layer 1 ----
  gemm1_fullk_kernel<<<ggrid, 256, 0, stream>>>(xbf, Bt1, xh1bf, a_s, a_d, as1, ad1, N);
  alpha_sm_kernel<<<gSM, 256, 0, stream>>>(rowptr, csr_src, ea_csr, a_s, a_d, Ve,
                                           alpha_t, self_t, N, E);
  agg_gather_h_kernel<1><<<gAG, 256, 0, stream>>>(xh1bf, alpha_t, self_t, rowptr, csr_src,
                                                  b1, h1bf, N, E);

  // ---- layer 2 ----
  gemm2_dbuf_kernel<<<ggrid, 256, 0, stream>>>(h1bf, Bt2, xh2bf, a_s, a_d, as2, ad2, N, 1024);
  alpha_sm_kernel<<<gSM, 256, 0, stream>>>(rowptr, csr_src, ea_csr, a_s, a_d, Ve + 256,
                                           alpha_t, self_t, N, E);
  agg_gather_h_kernel<0><<<gAG, 256, 0, stream>>>(xh2bf, alpha_t, self_t, rowptr, csr_src,
                                                  nullptr, xpart, N, E);
  head_reduce_kernel<<<(N * 32 + 255) / 256, 256, 0, stream>>>(xpart, b2, out, N);
}